// Round 9
// baseline (307.601 us; speedup 1.0000x reference)
//
#include <hip/hip_runtime.h>
#include <hip/hip_bf16.h>

typedef __hip_bfloat16 bf16;
typedef short short8 __attribute__((ext_vector_type(8)));
typedef float floatx4 __attribute__((ext_vector_type(4)));

#define S 256
#define H 512
#define P 32896            // S*(S+1)/2
#define NROWS 65792        // B*P
#define NEGF -1e30f
#define EPSF 1e-12f

// ---------------- ws layout (bytes) ----------------
#define OFF_LN1    2129920u    // f32 [B*S*H]
#define OFF_G1     3178496u    // f32 [B*S*H]
#define OFF_B1     4227072u    // f32 [B*S*H]
#define OFF_WCAT   5275648u    // bf16 [1024*512]
#define OFF_II     6324224u    // u16 [P]
#define OFF_JJ     6390016u    // u16 [P]
#define OFF_MU2    6455808u    // f32 [NROWS]
#define OFF_INV2   6718976u    // f32 [NROWS]
#define OFF_INNER  6982144u    // bf16 [NROWS*H]

// async 16B global->LDS (lane-linear dest: base + lane*16)
__device__ __forceinline__ void gld_lds16(const void* g, void* l) {
    __builtin_amdgcn_global_load_lds(
        (const __attribute__((address_space(1))) void*)g,
        (__attribute__((address_space(3))) void*)l, 16, 0, 0);
}

// ---------------- K1: ALL independent pre-work in ONE dispatch ----------------
// ids 0..511     : inner  (balanced pairing: CU c gets i=c and i=255-c -> 257 iters)
// ids 512..767   : g1b1   (128 row-groups x 2 mats; k-unroll x8)
// ids 768..831   : LN1
// ids 832..1855  : wcat transpose (64-col interleave, matches gemm epilogue)
// ids 1856..1984 : pair tables
// [R8 bug fixed: g1b1 had 512 ids but only needs 256 -> OOB writes into ws]
__global__ __launch_bounds__(256) void pre_kernel(
    const float* __restrict__ x, const float* __restrict__ mask,
    const float* __restrict__ lamtha,
    const float* __restrict__ Wg1, const float* __restrict__ Wb1,
    const float* __restrict__ g1, const float* __restrict__ b1,
    const float* __restrict__ Wg2, const float* __restrict__ Wb2,
    float* __restrict__ ln1, float* __restrict__ G1, float* __restrict__ B1,
    bf16* __restrict__ wcatT,
    unsigned short* __restrict__ ii, unsigned short* __restrict__ jj,
    bf16* __restrict__ inner) {
    __shared__ float sh_a[256];        // inner: maskadd
    __shared__ float sh_b[256];        // inner: reciprocal table
    __shared__ float rowbuf[4][H];     // g1b1
    __shared__ float part[4][8][2];    // LN1
    __shared__ float rstat[8][2];      // LN1
    const int id = blockIdx.x, tid = threadIdx.x;

    if (id < 512) {
        // ---- inner[p][h] = lam*mean + (1-lam)*max ----
        int t = id & 255, b = id >> 8;
        int i = b ? (255 - t) : t;
        sh_a[tid] = (1.0f - mask[b * S + tid]) * (-1000.0f);
        sh_b[tid] = 1.0f / (float)(tid + 1);   // same precise division, hoisted
        __syncthreads();
        int h2 = tid;
        float2 lam = ((const float2*)lamtha)[h2];
        float2 oml = {1.0f - lam.x, 1.0f - lam.y};
        const float2* xb = (const float2*)(x + (size_t)b * S * H);
        float2 mrun = {NEGF, NEGF};
        float2 srun = {0.0f, 0.0f};
        size_t base = (size_t)b * P + (size_t)(i * S - i * (i - 1) / 2);
        __hip_bfloat162* dst = (__hip_bfloat162*)inner;
        int j = i;
#define INNER_STEP(xx, jx)                                                 \
    {                                                                      \
        float ma = sh_a[jx];                                               \
        float vx = xx.x + ma, vy = xx.y + ma;                              \
        srun.x += vx;                                                      \
        srun.y += vy;                                                      \
        mrun.x = fmaxf(mrun.x, vx);                                        \
        mrun.y = fmaxf(mrun.y, vy);                                        \
        float rl = sh_b[(jx) - i];                                         \
        float fx = lam.x * (srun.x * rl) + oml.x * mrun.x;                 \
        float fy = lam.y * (srun.y * rl) + oml.y * mrun.y;                 \
        dst[(base + (size_t)((jx) - i)) * 256 + h2] =                      \
            __float22bfloat162_rn(make_float2(fx, fy));                    \
    }
        for (; j + 4 <= S; j += 4) {
            float2 x0 = xb[(j + 0) * 256 + h2];
            float2 x1 = xb[(j + 1) * 256 + h2];
            float2 x2 = xb[(j + 2) * 256 + h2];
            float2 x3 = xb[(j + 3) * 256 + h2];
            INNER_STEP(x0, j + 0)
            INNER_STEP(x1, j + 1)
            INNER_STEP(x2, j + 2)
            INNER_STEP(x3, j + 3)
        }
        for (; j < S; ++j) {
            float2 xv = xb[j * 256 + h2];
            INNER_STEP(xv, j)
        }
#undef INNER_STEP
    } else if (id < 768) {
        // ---- G1/B1 = bias + seq @ W1 (4 rows, 2 h-cols/thread, k-unroll x8) ----
        int sub = id - 512;                 // 0..255
        int grp = sub >> 1, mat = sub & 1;  // grp 0..127
        int h0 = tid, h1 = tid + 256;
        int r0 = grp * 4;                   // 0..508
#pragma unroll
        for (int r = 0; r < 4; ++r) {
            int row = r0 + r;
            float add = (1.0f - mask[row]) * (-1000.0f);
            rowbuf[r][h0] = x[(size_t)row * H + h0] + add;
            rowbuf[r][h1] = x[(size_t)row * H + h1] + add;
        }
        __syncthreads();
        const float* W = mat ? Wb1 : Wg1;
        float acc[4][2] = {{0, 0}, {0, 0}, {0, 0}, {0, 0}};
        for (int k8 = 0; k8 < 64; ++k8) {
            float4 ra[4][2];
#pragma unroll
            for (int r = 0; r < 4; ++r) {
                ra[r][0] = ((const float4*)rowbuf[r])[k8 * 2];
                ra[r][1] = ((const float4*)rowbuf[r])[k8 * 2 + 1];
            }
            float w0[8], w1[8];
#pragma unroll
            for (int kk = 0; kk < 8; ++kk) {
                w0[kk] = W[(size_t)(k8 * 8 + kk) * H + h0];
                w1[kk] = W[(size_t)(k8 * 8 + kk) * H + h1];
            }
#pragma unroll
            for (int r = 0; r < 4; ++r) {
                acc[r][0] += ra[r][0].x * w0[0] + ra[r][0].y * w0[1] +
                             ra[r][0].z * w0[2] + ra[r][0].w * w0[3] +
                             ra[r][1].x * w0[4] + ra[r][1].y * w0[5] +
                             ra[r][1].z * w0[6] + ra[r][1].w * w0[7];
                acc[r][1] += ra[r][0].x * w1[0] + ra[r][0].y * w1[1] +
                             ra[r][0].z * w1[2] + ra[r][0].w * w1[3] +
                             ra[r][1].x * w1[4] + ra[r][1].y * w1[5] +
                             ra[r][1].z * w1[6] + ra[r][1].w * w1[7];
            }
        }
        float bias0 = (mat ? b1 : g1)[h0];
        float bias1 = (mat ? b1 : g1)[h1];
        float* dst = mat ? B1 : G1;
#pragma unroll
        for (int r = 0; r < 4; ++r) {
            dst[(size_t)(r0 + r) * H + h0] = acc[r][0] + bias0;
            dst[(size_t)(r0 + r) * H + h1] = acc[r][1] + bias1;
        }
    } else if (id < 832) {
        // ---- LN1 (8 s-rows per block, 2 h-cols/thread) ----
        int blk = id - 768;                 // 0..63
        int b = blk >> 5, sc = blk & 31;
        int s0 = sc * 8;
        int wave = tid >> 6, lane = tid & 63;
        int h0 = tid, h1 = tid + 256;
        float v0[8], v1[8];
#pragma unroll
        for (int t = 0; t < 8; ++t) {
            int row = b * S + s0 + t;
            float add = (1.0f - mask[row]) * (-1000.0f);
            v0[t] = x[(size_t)row * H + h0] + add;
            v1[t] = x[(size_t)row * H + h1] + add;
        }
#pragma unroll
        for (int t = 0; t < 8; ++t) {
            float s = v0[t] + v1[t];
            float q = v0[t] * v0[t] + v1[t] * v1[t];
            for (int o = 1; o < 64; o <<= 1) { s += __shfl_xor(s, o); q += __shfl_xor(q, o); }
            if (lane == 0) { part[wave][t][0] = s; part[wave][t][1] = q; }
        }
        __syncthreads();
        if (tid < 16) {
            int row = tid >> 1, st = tid & 1;
            rstat[row][st] = part[0][row][st] + part[1][row][st] +
                             part[2][row][st] + part[3][row][st];
        }
        __syncthreads();
#pragma unroll
        for (int t = 0; t < 8; ++t) {
            float m = rstat[t][0] * (1.0f / 512.0f);
            float var = rstat[t][1] * (1.0f / 512.0f) - m * m;
            var = var < 0.0f ? 0.0f : var;
            float inv = rsqrtf(var + EPSF);
            int row = b * S + s0 + t;
            ln1[(size_t)row * H + h0] = (v0[t] - m) * inv;
            ln1[(size_t)row * H + h1] = (v1[t] - m) * inv;
        }
    } else if (id < 1856) {
        // ---- wcat transpose (64-col interleave; G2 rows 0..63, B2 rows 64..127 per htile) ----
        int n = id - 832;                   // 0..1023
        int tt = n >> 7, c = n & 127;
        int h = tt * 64 + (c & 63);
        const float* Wsrc = (c < 64) ? Wg2 : Wb2;
        int k0 = tid, k1 = tid + 256;
        wcatT[(size_t)n * H + k0] = __float2bfloat16(Wsrc[(size_t)k0 * H + h]);
        wcatT[(size_t)n * H + k1] = __float2bfloat16(Wsrc[(size_t)k1 * H + h]);
    } else {
        // ---- pair tables ----
        int p = (id - 1856) * 256 + tid;    // 129 blocks cover P=32896
        if (p >= P) return;
        float disc = 513.0f * 513.0f - 8.0f * (float)p;
        int i = (int)((513.0f - sqrtf(disc)) * 0.5f);
        i = i < 0 ? 0 : (i > S - 1 ? S - 1 : i);
        while (i > 0 && (i * S - i * (i - 1) / 2) > p) --i;
        while (i < S - 1 && ((i + 1) * S - (i + 1) * i / 2) <= p) ++i;
        int off = i * S - i * (i - 1) / 2;
        ii[p] = (unsigned short)i;
        jj[p] = (unsigned short)(i + (p - off));
    }
}

// ---------------- K2: LN2 row stats (i-centric, register-pinned G1/B1) ----------------
// 512 blocks, balanced pairing (CU c: i=c and i=255-c). 4 waves stripe j.
__global__ __launch_bounds__(256) void stats_kernel(
    const float* __restrict__ ln1, const float* __restrict__ G1,
    const float* __restrict__ B1,
    float* __restrict__ mu2, float* __restrict__ inv2) {
    int id = blockIdx.x;
    int t = id & 255, b = id >> 8;
    int i = b ? (255 - t) : t;
    int tid = threadIdx.x, wave = tid >> 6, lane = tid & 63;
    int off = i * S - i * (i - 1) / 2;
    const float4* gp = (const float4*)(G1 + (size_t)(b * S + i) * H);
    const float4* bp = (const float4*)(B1 + (size_t)(b * S + i) * H);
    float4 ga = gp[lane * 2], gb = gp[lane * 2 + 1];
    float4 ba = bp[lane * 2], bb = bp[lane * 2 + 1];
    for (int j = i + wave; j < S; j += 4) {
        const float4* lp = (const float4*)(ln1 + (size_t)(b * S + j) * H);
        float4 a0 = lp[lane * 2], a1 = lp[lane * 2 + 1];
        float v0 = a0.x * ga.x + ba.x, v1 = a0.y * ga.y + ba.y;
        float v2 = a0.z * ga.z + ba.z, v3 = a0.w * ga.w + ba.w;
        float v4 = a1.x * gb.x + bb.x, v5 = a1.y * gb.y + bb.y;
        float v6 = a1.z * gb.z + bb.z, v7 = a1.w * gb.w + bb.w;
        float sum = ((v0 + v1) + (v2 + v3)) + ((v4 + v5) + (v6 + v7));
        float ss = ((v0 * v0 + v1 * v1) + (v2 * v2 + v3 * v3)) +
                   ((v4 * v4 + v5 * v5) + (v6 * v6 + v7 * v7));
        for (int o = 1; o < 64; o <<= 1) { sum += __shfl_xor(sum, o); ss += __shfl_xor(ss, o); }
        if (lane == 0) {
            int r = b * P + off + (j - i);
            float m = sum * (1.0f / 512.0f);
            float var = ss * (1.0f / 512.0f) - m * m;
            var = var < 0.0f ? 0.0f : var;
            mu2[r] = m;
            inv2[r] = rsqrtf(var + EPSF);
        }
    }
}

// ---------------- fused GEMM (inner @ [Wg2|Wb2]) + LN2 epilogue ----------------
// EXACT R3/R6/R7 kernel (measured 96-98 us, MfmaUtil ~29, FETCH ~48 MB, 0 bank conf).
__global__ __launch_bounds__(256, 2) void gemm_kernel(
    const bf16* __restrict__ inner, const bf16* __restrict__ wcatT,
    const float* __restrict__ g2, const float* __restrict__ b2,
    const float* __restrict__ ln1, const float* __restrict__ G1, const float* __restrict__ B1,
    const unsigned short* __restrict__ ii, const unsigned short* __restrict__ jj,
    const float* __restrict__ mu2, const float* __restrict__ inv2,
    float* __restrict__ out) {
    extern __shared__ __align__(16) char smem[];   // 65536: 2 bufs x (A 16K | B 16K)

    const int tid = threadIdx.x;
    const int wave = tid >> 6, lane = tid & 63;
    const int q = lane >> 4, l15 = lane & 15;
    const int wm = wave & 1, wn = wave >> 1;       // wm 0..1, wn 0..1

    const int id = blockIdx.x;
    int rb, t;
    if (id < 4096) { rb = (id >> 6) * 8 + (id & 7); t = (id >> 3) & 7; }
    else           { int w = id - 4096; rb = 512 + (w & 1); t = w >> 1; }
    const int R0 = rb * 128;

    const int srow = tid >> 3;                    // 0..31
    const int sx8 = ((tid & 7) ^ (srow & 7)) * 8;
    const bf16* const Ag = inner + (size_t)(R0 + srow) * H + sx8;
    const bf16* const Bg = wcatT + (size_t)(t * 128 + srow) * H + sx8;

    char* const A0 = smem;
    char* const B0 = smem + 16384;
    char* const A1 = smem + 32768;
    char* const B1s = smem + 49152;

    floatx4 acc[4][4];
#pragma unroll
    for (int a = 0; a < 4; ++a)
#pragma unroll
        for (int c = 0; c < 4; ++c) acc[a][c] = (floatx4){0.f, 0.f, 0.f, 0.f};

    auto STAGE = [&](int kt, char* Ad, char* Bd) {
#pragma unroll
        for (int i2 = 0; i2 < 4; ++i2)
            gld_lds16(Ag + (size_t)i2 * 32 * H + kt * 64, Ad + i2 * 4096 + wave * 1024);
#pragma unroll
        for (int i2 = 0; i2 < 4; ++i2)
            gld_lds16(Bg + (size_t)i2 * 32 * H + kt * 64, Bd + i2 * 4096 + wave * 1024);
    };

    STAGE(0, A0, B0);
    STAGE(1, A1, B1s);
    asm volatile("s_waitcnt vmcnt(8)" ::: "memory");
    asm volatile("s_barrier" ::: "memory");

#pragma unroll
    for (int kt = 0; kt < 8; ++kt) {
        char* const As = (kt & 1) ? A1 : A0;
        char* const Bs = (kt & 1) ? B1s : B0;

        short8 bfr[4][2], af[4][2];
#pragma unroll
        for (int ks = 0; ks < 2; ++ks) {
#pragma unroll
            for (int fn = 0; fn < 4; ++fn) {
                int nr = (fn < 2 ? wn * 32 + fn * 16 : 64 + wn * 32 + (fn - 2) * 16) + l15;
                bfr[fn][ks] = *(const short8*)(Bs + nr * 128 + (((ks * 4 + q) ^ (l15 & 7)) << 4));
            }
#pragma unroll
            for (int fm = 0; fm < 4; ++fm) {
                int mr = wm * 64 + fm * 16 + l15;
                af[fm][ks] = *(const short8*)(As + mr * 128 + (((ks * 4 + q) ^ (l15 & 7)) << 4));
            }
        }

        __builtin_amdgcn_s_setprio(1);
#pragma unroll
        for (int fm = 0; fm < 4; ++fm)
#pragma unroll
            for (int fn = 0; fn < 4; ++fn)
                acc[fm][fn] = __builtin_amdgcn_mfma_f32_16x16x32_bf16(af[fm][0], bfr[fn][0], acc[fm][fn], 0, 0, 0);
        __builtin_amdgcn_s_setprio(0);

        if (kt < 6) {
            asm volatile("s_waitcnt lgkmcnt(0)" ::: "memory");
            asm volatile("s_barrier" ::: "memory");
            STAGE(kt + 2, As, Bs);
        }

        __builtin_amdgcn_s_setprio(1);
#pragma unroll
        for (int fm = 0; fm < 4; ++fm)
#pragma unroll
            for (int fn = 0; fn < 4; ++fn)
                acc[fm][fn] = __builtin_amdgcn_mfma_f32_16x16x32_bf16(af[fm][1], bfr[fn][1], acc[fm][fn], 0, 0, 0);
        __builtin_amdgcn_s_setprio(0);

        if (kt < 6) {
            asm volatile("s_waitcnt vmcnt(8)" ::: "memory");
            asm volatile("s_barrier" ::: "memory");
        } else if (kt == 6) {
            asm volatile("s_waitcnt vmcnt(0)" ::: "memory");
            asm volatile("s_barrier" ::: "memory");
        }
    }

    // ---- register-only LN2 epilogue (all 4 waves, no LDS, no barriers) ----
    float g2v[2], b2v[2];
#pragma unroll
    for (int fg = 0; fg < 2; ++fg) {
        int h = t * 64 + wn * 32 + fg * 16 + l15;
        g2v[fg] = g2[h];
        b2v[fg] = b2[h];
    }
#pragma unroll
    for (int fm = 0; fm < 4; ++fm) {
#pragma unroll
        for (int r = 0; r < 4; ++r) {
            int m = wm * 64 + fm * 16 + q * 4 + r;
            int rg = R0 + m;
            int b = (rg >= P) ? 1 : 0;
            int p = rg - b * P;
            int i = ii[p], j = jj[p];
            float mu = mu2[rg], iv = inv2[rg];
            const float* lp = ln1 + (size_t)(b * S + j) * H + t * 64 + wn * 32;
            const float* gp = G1 + (size_t)(b * S + i) * H + t * 64 + wn * 32;
            const float* bp = B1 + (size_t)(b * S + i) * H + t * 64 + wn * 32;
            float* op = out + (size_t)rg * H + t * 64 + wn * 32;
#pragma unroll
            for (int fg = 0; fg < 2; ++fg) {
                int c = fg * 16 + l15;
                float s = (lp[c] * gp[c] + bp[c] - mu) * iv;
                float G2v = acc[fm][fg][r] + g2v[fg];
                float B2v = acc[fm][fg + 2][r] + b2v[fg];
                op[c] = s * G2v + B2v;
            }
        }
    }
}

// ---------------- launcher ----------------
extern "C" void kernel_launch(void* const* d_in, const int* in_sizes, int n_in,
                              void* d_out, int out_size, void* d_ws, size_t ws_size,
                              hipStream_t stream) {
    const float* x = (const float*)d_in[0];
    const float* mask = (const float*)d_in[1];
    const float* lamtha = (const float*)d_in[2];
    const float* Wg1 = (const float*)d_in[3];
    const float* Wb1 = (const float*)d_in[4];
    const float* g1 = (const float*)d_in[5];
    const float* b1 = (const float*)d_in[6];
    const float* Wg2 = (const float*)d_in[7];
    const float* Wb2 = (const float*)d_in[8];
    const float* g2 = (const float*)d_in[9];
    const float* b2 = (const float*)d_in[10];
    float* out = (float*)d_out;

    char* ws = (char*)d_ws;
    float* ln1 = (float*)(ws + OFF_LN1);
    float* G1 = (float*)(ws + OFF_G1);
    float* B1 = (float*)(ws + OFF_B1);
    bf16* wcatT = (bf16*)(ws + OFF_WCAT);
    unsigned short* iiA = (unsigned short*)(ws + OFF_II);
    unsigned short* jjA = (unsigned short*)(ws + OFF_JJ);
    float* mu2 = (float*)(ws + OFF_MU2);
    float* inv2 = (float*)(ws + OFF_INV2);
    bf16* inner = (bf16*)(ws + OFF_INNER);

    static bool attr_set = false;
    if (!attr_set) {
        hipFuncSetAttribute((const void*)gemm_kernel,
                            hipFuncAttributeMaxDynamicSharedMemorySize, 65536);
        attr_set = true;
    }

    hipLaunchKernelGGL(pre_kernel, dim3(1985), dim3(256), 0, stream,
                       x, mask, lamtha, Wg1, Wb1, g1, b1, Wg2, Wb2,
                       ln1, G1, B1, wcatT, iiA, jjA, inner);
    hipLaunchKernelGGL(stats_kernel, dim3(512), dim3(256), 0, stream,
                       ln1, G1, B1, mu2, inv2);
    hipLaunchKernelGGL(gemm_kernel, dim3(4112), dim3(256), 65536, stream,
                       inner, wcatT, g2, b2, ln1, G1, B1, iiA, jjA, mu2, inv2, out);
}

// Round 10
// 306.934 us; speedup vs baseline: 1.0022x; 1.0022x over previous
//
#include <hip/hip_runtime.h>
#include <hip/hip_bf16.h>

typedef __hip_bfloat16 bf16;
typedef short short8 __attribute__((ext_vector_type(8)));
typedef float floatx4 __attribute__((ext_vector_type(4)));

#define S 256
#define H 512
#define P 32896            // S*(S+1)/2
#define NROWS 65792        // B*P
#define NEGF -1e30f
#define EPSF 1e-12f

// ---------------- ws layout (bytes) ----------------
#define OFF_LN1    2129920u    // f32 [B*S*H]
#define OFF_G1     3178496u    // f32 [B*S*H]
#define OFF_B1     4227072u    // f32 [B*S*H]
#define OFF_WCAT   5275648u    // bf16 [1024*512]
#define OFF_II     6324224u    // u16 [P]
#define OFF_JJ     6390016u    // u16 [P]
#define OFF_MU2    6455808u    // f32 [NROWS]
#define OFF_INV2   6718976u    // f32 [NROWS]
#define OFF_INNER  6982144u    // bf16 [NROWS*H]

// async 16B global->LDS (lane-linear dest: base + lane*16)
__device__ __forceinline__ void gld_lds16(const void* g, void* l) {
    __builtin_amdgcn_global_load_lds(
        (const __attribute__((address_space(1))) void*)g,
        (__attribute__((address_space(3))) void*)l, 16, 0, 0);
}

// ---------------- fused A: LN1 (blocks 0..63) | prep (64..1152) ----------------
// prep: wcatT rows for GEMM htile t = [t*128, t*128+128). Local row u:
// wn = u>>6 (wave N-half), v = u&63: v<32 -> G2 col t*64+wn*32+v,
// v>=32 -> MATCHING B2 col t*64+wn*32+(v-32). Each gemm wave then owns
// matching G2 (fn 0,1) / B2 (fn 2,3) fragments -> register-only LN2 epilogue.
__global__ __launch_bounds__(512) void fusedA_kernel(
    const float* __restrict__ x, const float* __restrict__ mask,
    float* __restrict__ ln1,
    const float* __restrict__ Wg2, const float* __restrict__ Wb2,
    bf16* __restrict__ wcatT,
    unsigned short* __restrict__ ii, unsigned short* __restrict__ jj) {
    __shared__ float part[8][8][2];
    __shared__ float rstat[8][2];
    if (blockIdx.x < 64) {
        // ---- LN1 (8 s-rows per block); seq computed inline ----
        int b = blockIdx.x >> 5, sc = blockIdx.x & 31, h = threadIdx.x;
        int wave = h >> 6, lane = h & 63;
        int s0 = sc * 8;
        float v[8];
#pragma unroll
        for (int t = 0; t < 8; ++t) {
            int s = s0 + t;
            v[t] = x[(size_t)(b * S + s) * H + h] + (1.0f - mask[b * S + s]) * (-1000.0f);
        }
#pragma unroll
        for (int t = 0; t < 8; ++t) {
            float s = v[t], q = v[t] * v[t];
            for (int o = 1; o < 64; o <<= 1) { s += __shfl_xor(s, o); q += __shfl_xor(q, o); }
            if (lane == 0) { part[wave][t][0] = s; part[wave][t][1] = q; }
        }
        __syncthreads();
        if (h < 16) {
            int row = h >> 1, st = h & 1;
            float a = 0.0f;
#pragma unroll
            for (int w = 0; w < 8; ++w) a += part[w][row][st];
            rstat[row][st] = a;
        }
        __syncthreads();
#pragma unroll
        for (int t = 0; t < 8; ++t) {
            float m = rstat[t][0] * (1.0f / 512.0f);
            float var = rstat[t][1] * (1.0f / 512.0f) - m * m;
            var = var < 0.0f ? 0.0f : var;
            float inv = rsqrtf(var + EPSF);
            ln1[(size_t)(b * S + s0 + t) * H + h] = (v[t] - m) * inv;
        }
    } else {
        int n = blockIdx.x - 64;
        if (n < 1024) {
            int k = threadIdx.x;
            int tt = n >> 7, u = n & 127;
            int wnn = u >> 6, v = u & 63;
            int h = tt * 64 + wnn * 32 + (v & 31);
            float val = (v < 32) ? Wg2[(size_t)k * H + h] : Wb2[(size_t)k * H + h];
            wcatT[(size_t)n * H + k] = __float2bfloat16(val);
        } else {
            int p = (n - 1024) * 512 + threadIdx.x;
            if (p >= P) return;
            float disc = 513.0f * 513.0f - 8.0f * (float)p;
            int i = (int)((513.0f - sqrtf(disc)) * 0.5f);
            i = i < 0 ? 0 : (i > S - 1 ? S - 1 : i);
            while (i > 0 && (i * S - i * (i - 1) / 2) > p) --i;
            while (i < S - 1 && ((i + 1) * S - (i + 1) * i / 2) <= p) ++i;
            int off = i * S - i * (i - 1) / 2;
            ii[p] = (unsigned short)i;
            jj[p] = (unsigned short)(i + (p - off));
        }
    }
}

// ---------------- G1/B1 = bias + seq @ W1 (seq inline; k-unroll x8) ----------------
__global__ __launch_bounds__(256) void g1b1_kernel(
    const float* __restrict__ x, const float* __restrict__ mask,
    const float* __restrict__ Wg1, const float* __restrict__ Wb1,
    const float* __restrict__ g1, const float* __restrict__ b1,
    float* __restrict__ G1, float* __restrict__ B1) {
    __shared__ float rowbuf[4][H];
    int grp = blockIdx.x;   // 0..127
    int mat = blockIdx.y;   // 0..1
    int tid = threadIdx.x;
    int h0 = tid, h1 = tid + 256;
    int r0 = grp * 4;
#pragma unroll
    for (int r = 0; r < 4; ++r) {
        int row = r0 + r;
        float add = (1.0f - mask[row]) * (-1000.0f);
        rowbuf[r][h0] = x[(size_t)row * H + h0] + add;
        rowbuf[r][h1] = x[(size_t)row * H + h1] + add;
    }
    __syncthreads();
    const float* W = mat ? Wb1 : Wg1;
    float acc[4][2] = {{0, 0}, {0, 0}, {0, 0}, {0, 0}};
    for (int k8 = 0; k8 < 64; ++k8) {
        float4 ra[4][2];
#pragma unroll
        for (int r = 0; r < 4; ++r) {
            ra[r][0] = ((const float4*)rowbuf[r])[k8 * 2];
            ra[r][1] = ((const float4*)rowbuf[r])[k8 * 2 + 1];
        }
        float w0[8], w1[8];
#pragma unroll
        for (int kk = 0; kk < 8; ++kk) {
            w0[kk] = W[(size_t)(k8 * 8 + kk) * H + h0];
            w1[kk] = W[(size_t)(k8 * 8 + kk) * H + h1];
        }
#pragma unroll
        for (int r = 0; r < 4; ++r) {
            acc[r][0] += ra[r][0].x * w0[0] + ra[r][0].y * w0[1] +
                         ra[r][0].z * w0[2] + ra[r][0].w * w0[3] +
                         ra[r][1].x * w0[4] + ra[r][1].y * w0[5] +
                         ra[r][1].z * w0[6] + ra[r][1].w * w0[7];
            acc[r][1] += ra[r][0].x * w1[0] + ra[r][0].y * w1[1] +
                         ra[r][0].z * w1[2] + ra[r][0].w * w1[3] +
                         ra[r][1].x * w1[4] + ra[r][1].y * w1[5] +
                         ra[r][1].z * w1[6] + ra[r][1].w * w1[7];
        }
    }
    float bias0 = (mat ? b1 : g1)[h0];
    float bias1 = (mat ? b1 : g1)[h1];
    float* dst = mat ? B1 : G1;
#pragma unroll
    for (int r = 0; r < 4; ++r) {
        dst[(size_t)(r0 + r) * H + h0] = acc[r][0] + bias0;
        dst[(size_t)(r0 + r) * H + h1] = acc[r][1] + bias1;
    }
}

// ---------------- co-scheduled: inner (even ids) | LN2 row stats (odd ids) ----------------
// R7 arrangement (best measured) + R9-verified micro-opts: reciprocal LDS
// table (kills the per-step precise division) and packed bf16x2 convert.
__global__ __launch_bounds__(256) void innerstats_kernel(
    const float* __restrict__ x, const float* __restrict__ mask,
    const float* __restrict__ lamtha,
    const float* __restrict__ ln1, const float* __restrict__ G1,
    const float* __restrict__ B1,
    bf16* __restrict__ inner, float* __restrict__ mu2, float* __restrict__ inv2) {
    __shared__ float sh_a[256];
    __shared__ float sh_b[256];
    int id = blockIdx.x;
    int kind = id & 1, sub = id >> 1;
    int t = sub & 255, b = sub >> 8;
    int i = b ? (255 - t) : t;
    int tid = threadIdx.x;
    int off = i * S - i * (i - 1) / 2;

    if (kind == 0) {
        // ---- inner ----
        int h2 = tid;                 // float2 index, 0..255
        sh_a[tid] = (1.0f - mask[b * S + tid]) * (-1000.0f);
        sh_b[tid] = 1.0f / (float)(tid + 1);
        __syncthreads();
        float2 lam = ((const float2*)lamtha)[h2];
        float2 oml = {1.0f - lam.x, 1.0f - lam.y};
        const float2* xb = (const float2*)(x + (size_t)b * S * H);
        float2 mrun = {NEGF, NEGF};
        float2 srun = {0.0f, 0.0f};
        size_t base = (size_t)b * P + (size_t)off;
        __hip_bfloat162* dst = (__hip_bfloat162*)inner;
        int j = i;
#define INNER_STEP(xx, jx)                                                 \
    {                                                                      \
        float ma = sh_a[jx];                                               \
        float vx = xx.x + ma, vy = xx.y + ma;                              \
        srun.x += vx;                                                      \
        srun.y += vy;                                                      \
        mrun.x = fmaxf(mrun.x, vx);                                        \
        mrun.y = fmaxf(mrun.y, vy);                                        \
        float rl = sh_b[(jx) - i];                                         \
        float fx = lam.x * (srun.x * rl) + oml.x * mrun.x;                 \
        float fy = lam.y * (srun.y * rl) + oml.y * mrun.y;                 \
        dst[(base + (size_t)((jx) - i)) * 256 + h2] =                      \
            __float22bfloat162_rn(make_float2(fx, fy));                    \
    }
        for (; j + 4 <= S; j += 4) {
            float2 x0 = xb[(j + 0) * 256 + h2];
            float2 x1 = xb[(j + 1) * 256 + h2];
            float2 x2 = xb[(j + 2) * 256 + h2];
            float2 x3 = xb[(j + 3) * 256 + h2];
            INNER_STEP(x0, j + 0)
            INNER_STEP(x1, j + 1)
            INNER_STEP(x2, j + 2)
            INNER_STEP(x3, j + 3)
        }
        for (; j < S; ++j) {
            float2 xv = xb[j * 256 + h2];
            INNER_STEP(xv, j)
        }
#undef INNER_STEP
    } else {
        // ---- stats (i-centric, register-pinned G1/B1) ----
        int wave = tid >> 6, lane = tid & 63;
        const float4* gp = (const float4*)(G1 + (size_t)(b * S + i) * H);
        const float4* bp = (const float4*)(B1 + (size_t)(b * S + i) * H);
        float4 ga = gp[lane * 2], gb = gp[lane * 2 + 1];
        float4 ba = bp[lane * 2], bb = bp[lane * 2 + 1];
        for (int j = i + wave; j < S; j += 4) {
            const float4* lp = (const float4*)(ln1 + (size_t)(b * S + j) * H);
            float4 a0 = lp[lane * 2], a1 = lp[lane * 2 + 1];
            float v0 = a0.x * ga.x + ba.x, v1 = a0.y * ga.y + ba.y;
            float v2 = a0.z * ga.z + ba.z, v3 = a0.w * ga.w + ba.w;
            float v4 = a1.x * gb.x + bb.x, v5 = a1.y * gb.y + bb.y;
            float v6 = a1.z * gb.z + bb.z, v7 = a1.w * gb.w + bb.w;
            float sum = ((v0 + v1) + (v2 + v3)) + ((v4 + v5) + (v6 + v7));
            float ss = ((v0 * v0 + v1 * v1) + (v2 * v2 + v3 * v3)) +
                       ((v4 * v4 + v5 * v5) + (v6 * v6 + v7 * v7));
            for (int o = 1; o < 64; o <<= 1) { sum += __shfl_xor(sum, o); ss += __shfl_xor(ss, o); }
            if (lane == 0) {
                int r = b * P + off + (j - i);
                float m = sum * (1.0f / 512.0f);
                float var = ss * (1.0f / 512.0f) - m * m;
                var = var < 0.0f ? 0.0f : var;
                mu2[r] = m;
                inv2[r] = rsqrtf(var + EPSF);
            }
        }
    }
}

// ---------------- fused GEMM (inner @ [Wg2|Wb2]) + LN2 epilogue ----------------
// 256x128 tile, 4 waves (2M x 2N, wave-tile 128x64), BK=32, LDS 48 KB dbuf
// -> 2 blocks/CU (VGPR ~210 @ (256,2): no spill, unlike R5's (512,4)).
// Read-side LDS bytes/MAC 0.046 vs R3's 0.061 (1.33x) while keeping R3's
// 2-block mutual phase-hiding. BK=32 rows (64 B) stored PAIRED: one 128-B
// phys row = two logical rows, chunks XOR'd by (prow&7) [R5 hardware-verified
// swizzle; all fragment bases ==0 mod 8 so the algebra carries verbatim].
// Pipeline: stage kt+2 after lgkmcnt(0)+barrier mid-kt; steady vmcnt(6).
// Grid 2056 = 257 panels x 8 htiles (65792 = 257*256: no tail); panel's 8
// htiles all at ids == p (mod 8) -> one XCD (A-panel HBM-fetched once).
__global__ __launch_bounds__(256, 2) void gemm_kernel(
    const bf16* __restrict__ inner, const bf16* __restrict__ wcatT,
    const float* __restrict__ g2, const float* __restrict__ b2,
    const float* __restrict__ ln1, const float* __restrict__ G1, const float* __restrict__ B1,
    const unsigned short* __restrict__ ii, const unsigned short* __restrict__ jj,
    const float* __restrict__ mu2, const float* __restrict__ inv2,
    float* __restrict__ out) {
    extern __shared__ __align__(16) char smem[];   // 49152: 2 bufs x (A 16K | B 8K)

    const int tid = threadIdx.x;
    const int wave = tid >> 6, lane = tid & 63;
    const int q = lane >> 4, l15 = lane & 15;
    const int wm = wave & 1, wn = wave >> 1;       // wm 0..1, wn 0..1

    const int id = blockIdx.x;
    int rb, t;
    if (id < 2048) { rb = (id >> 6) * 8 + (id & 7); t = (id >> 3) & 7; }
    else           { rb = 256; t = id - 2048; }
    const int R0 = rb * 256;

    // staging source decode (inverse of paired-row swizzle): chunk ci ->
    // phys row pr = ci>>3, phys chunk pc = ci&7; logical l = pc ^ (pr&7);
    // logical row = 2*pr + (l>>2), col-quad cq = l&3.
    int arow[4], acq[4];
#pragma unroll
    for (int s2 = 0; s2 < 4; ++s2) {
        int ci = s2 * 256 + tid;
        int pr = ci >> 3, pc = ci & 7, l = pc ^ (pr & 7);
        arow[s2] = (pr << 1) | (l >> 2);
        acq[s2] = l & 3;
    }
    const bf16* Asrc0 = inner + (size_t)(R0 + arow[0]) * H + acq[0] * 8;
    const bf16* Asrc1 = inner + (size_t)(R0 + arow[1]) * H + acq[1] * 8;
    const bf16* Asrc2 = inner + (size_t)(R0 + arow[2]) * H + acq[2] * 8;
    const bf16* Asrc3 = inner + (size_t)(R0 + arow[3]) * H + acq[3] * 8;
    const bf16* Bsrc0 = wcatT + (size_t)(t * 128 + arow[0]) * H + acq[0] * 8;
    const bf16* Bsrc1 = wcatT + (size_t)(t * 128 + arow[1]) * H + acq[1] * 8;

    char* const A0 = smem;
    char* const B0 = smem + 16384;
    char* const A1 = smem + 24576;
    char* const B1s = smem + 40960;

    // read-side lane constants (R5-verified): prl = phys row in 8-row group,
    // logical chunk (half<<2)|q XOR'd back by prl.
    const int prl = l15 >> 1;
    const int apc = ((((l15 & 1) << 2) | q) ^ prl) << 4;
    const int C = prl * 128 + apc;

    floatx4 acc[8][4];
#pragma unroll
    for (int a = 0; a < 8; ++a)
#pragma unroll
        for (int c = 0; c < 4; ++c) acc[a][c] = (floatx4){0.f, 0.f, 0.f, 0.f};

    auto STAGE = [&](int kt, char* Ad, char* Bd) {
        gld_lds16(Asrc0 + kt * 32, Ad + 0 * 4096 + wave * 1024);
        gld_lds16(Asrc1 + kt * 32, Ad + 1 * 4096 + wave * 1024);
        gld_lds16(Asrc2 + kt * 32, Ad + 2 * 4096 + wave * 1024);
        gld_lds16(Asrc3 + kt * 32, Ad + 3 * 4096 + wave * 1024);
        gld_lds16(Bsrc0 + kt * 32, Bd + 0 * 4096 + wave * 1024);
        gld_lds16(Bsrc1 + kt * 32, Bd + 1 * 4096 + wave * 1024);
    };

    // prologue: fill both buffers; wait only the first (6 loads stay in flight)
    STAGE(0, A0, B0);
    STAGE(1, A1, B1s);
    asm volatile("s_waitcnt vmcnt(6)" ::: "memory");
    asm volatile("s_barrier" ::: "memory");

#pragma unroll
    for (int kt = 0; kt < 16; ++kt) {
        char* const As = (kt & 1) ? A1 : A0;
        char* const Bs = (kt & 1) ? B1s : B0;

        short8 af[8], bfr[4];
#pragma unroll
        for (int fn = 0; fn < 4; ++fn)
            bfr[fn] = *(const short8*)(Bs + wn * 4096 + fn * 1024 + C);
#pragma unroll
        for (int fm = 0; fm < 8; ++fm)
            af[fm] = *(const short8*)(As + wm * 8192 + fm * 1024 + C);

        __builtin_amdgcn_s_setprio(1);
#pragma unroll
        for (int fm = 0; fm < 4; ++fm)
#pragma unroll
            for (int fn = 0; fn < 4; ++fn)
                acc[fm][fn] = __builtin_amdgcn_mfma_f32_16x16x32_bf16(af[fm], bfr[fn], acc[fm][fn], 0, 0, 0);
        __builtin_amdgcn_s_setprio(0);

        if (kt < 14) {
            // all my LDS reads done -> barrier -> buffer dead, refill with kt+2
            asm volatile("s_waitcnt lgkmcnt(0)" ::: "memory");
            asm volatile("s_barrier" ::: "memory");
            STAGE(kt + 2, As, Bs);
        }

        __builtin_amdgcn_s_setprio(1);
#pragma unroll
        for (int fm = 4; fm < 8; ++fm)
#pragma unroll
            for (int fn = 0; fn < 4; ++fn)
                acc[fm][fn] = __builtin_amdgcn_mfma_f32_16x16x32_bf16(af[fm], bfr[fn], acc[fm][fn], 0, 0, 0);
        __builtin_amdgcn_s_setprio(0);

        if (kt < 14) {
            // wait kt+1's 6 loads (kt+2's 6 remain in flight across the barrier)
            asm volatile("s_waitcnt vmcnt(6)" ::: "memory");
            asm volatile("s_barrier" ::: "memory");
        } else if (kt == 14) {
            asm volatile("s_waitcnt vmcnt(0)" ::: "memory");
            asm volatile("s_barrier" ::: "memory");
        }
    }

    // ---- register-only LN2 epilogue (all 4 waves, no LDS, no barriers) ----
    float g2v[2], b2v[2];
#pragma unroll
    for (int fg = 0; fg < 2; ++fg) {
        int h = t * 64 + wn * 32 + fg * 16 + l15;
        g2v[fg] = g2[h];
        b2v[fg] = b2[h];
    }
#pragma unroll
    for (int fm = 0; fm < 8; ++fm) {
#pragma unroll
        for (int r = 0; r < 4; ++r) {
            int m = wm * 128 + fm * 16 + q * 4 + r;
            int rg = R0 + m;
            int b = (rg >= P) ? 1 : 0;
            int p = rg - b * P;
            int i = ii[p], j = jj[p];
            float mu = mu2[rg], iv = inv2[rg];
            const float* lp = ln1 + (size_t)(b * S + j) * H + t * 64 + wn * 32;
            const float* gp = G1 + (size_t)(b * S + i) * H + t * 64 + wn * 32;
            const float* bp = B1 + (size_t)(b * S + i) * H + t * 64 + wn * 32;
            float* op = out + (size_t)rg * H + t * 64 + wn * 32;
#pragma unroll
            for (int fg = 0; fg < 2; ++fg) {
                int c = fg * 16 + l15;
                float s = (lp[c] * gp[c] + bp[c] - mu) * iv;
                float G2v = acc[fm][fg][r] + g2v[fg];
                float B2v = acc[fm][fg + 2][r] + b2v[fg];
                op[c] = s * G2v + B2v;
            }
        }
    }
}

// ---------------- launcher ----------------
extern "C" void kernel_launch(void* const* d_in, const int* in_sizes, int n_in,
                              void* d_out, int out_size, void* d_ws, size_t ws_size,
                              hipStream_t stream) {
    const float* x = (const float*)d_in[0];
    const float* mask = (const float*)d_in[1];
    const float* lamtha = (const float*)d_in[2];
    const float* Wg1 = (const float*)d_in[3];
    const float* Wb1 = (const float*)d_in[4];
    const float* g1 = (const float*)d_in[5];
    const float* b1 = (const float*)d_in[6];
    const float* Wg2 = (const float*)d_in[7];
    const float* Wb2 = (const float*)d_in[8];
    const float* g2 = (const float*)d_in[9];
    const float* b2 = (const float*)d_in[10];
    float* out = (float*)d_out;

    char* ws = (char*)d_ws;
    float* ln1 = (float*)(ws + OFF_LN1);
    float* G1 = (float*)(ws + OFF_G1);
    float* B1 = (float*)(ws + OFF_B1);
    bf16* wcatT = (bf16*)(ws + OFF_WCAT);
    unsigned short* iiA = (unsigned short*)(ws + OFF_II);
    unsigned short* jjA = (unsigned short*)(ws + OFF_JJ);
    float* mu2 = (float*)(ws + OFF_MU2);
    float* inv2 = (float*)(ws + OFF_INV2);
    bf16* inner = (bf16*)(ws + OFF_INNER);

    static bool attr_set = false;
    if (!attr_set) {
        hipFuncSetAttribute((const void*)gemm_kernel,
                            hipFuncAttributeMaxDynamicSharedMemorySize, 49152);
        attr_set = true;
    }

    hipLaunchKernelGGL(fusedA_kernel, dim3(1153), dim3(512), 0, stream,
                       x, mask, ln1, Wg2, Wb2, wcatT, iiA, jjA);
    hipLaunchKernelGGL(g1b1_kernel, dim3(128, 2), dim3(256), 0, stream,
                       x, mask, Wg1, Wb1, g1, b1, G1, B1);
    hipLaunchKernelGGL(innerstats_kernel, dim3(1024), dim3(256), 0, stream,
                       x, mask, lamtha, ln1, G1, B1, inner, mu2, inv2);
    hipLaunchKernelGGL(gemm_kernel, dim3(2056), dim3(256), 49152, stream,
                       inner, wcatT, g2, b2, ln1, G1, B1, iiA, jjA, mu2, inv2, out);
}

// Round 11
// 305.874 us; speedup vs baseline: 1.0056x; 1.0035x over previous
//
#include <hip/hip_runtime.h>
#include <hip/hip_bf16.h>

typedef __hip_bfloat16 bf16;
typedef short short8 __attribute__((ext_vector_type(8)));
typedef float floatx4 __attribute__((ext_vector_type(4)));

#define S 256
#define H 512
#define P 32896            // S*(S+1)/2
#define NROWS 65792        // B*P
#define NEGF -1e30f
#define EPSF 1e-12f

// ---------------- ws layout (bytes) ----------------
#define OFF_LN1    2129920u    // f32 [B*S*H]
#define OFF_G1     3178496u    // f32 [B*S*H]
#define OFF_B1     4227072u    // f32 [B*S*H]
#define OFF_WCAT   5275648u    // bf16 [1024*512]
#define OFF_II     6324224u    // u16 [P]
#define OFF_JJ     6390016u    // u16 [P]
#define OFF_MU2    6455808u    // f32 [NROWS]
#define OFF_INV2   6718976u    // f32 [NROWS]
#define OFF_INNER  6982144u    // bf16 [NROWS*H]

// async 16B global->LDS (lane-linear dest: base + lane*16)
__device__ __forceinline__ void gld_lds16(const void* g, void* l) {
    __builtin_amdgcn_global_load_lds(
        (const __attribute__((address_space(1))) void*)g,
        (__attribute__((address_space(3))) void*)l, 16, 0, 0);
}

// ---------------- fused A: LN1 (blocks 0..63) | prep (64..1152) ----------------
// prep [R7-verified 64-col interleave]: GEMM htile t uses wcatT rows
// [t*128, t*128+128): local rows 0..63 = G2 cols t*64..t*64+63, local rows
// 64..127 = MATCHING B2 cols -> register-only LN2 epilogue in gemm.
__global__ __launch_bounds__(512) void fusedA_kernel(
    const float* __restrict__ x, const float* __restrict__ mask,
    float* __restrict__ ln1,
    const float* __restrict__ Wg2, const float* __restrict__ Wb2,
    bf16* __restrict__ wcatT,
    unsigned short* __restrict__ ii, unsigned short* __restrict__ jj) {
    __shared__ float part[8][8][2];
    __shared__ float rstat[8][2];
    if (blockIdx.x < 64) {
        // ---- LN1 (8 s-rows per block); seq computed inline ----
        int b = blockIdx.x >> 5, sc = blockIdx.x & 31, h = threadIdx.x;
        int wave = h >> 6, lane = h & 63;
        int s0 = sc * 8;
        float v[8];
#pragma unroll
        for (int t = 0; t < 8; ++t) {
            int s = s0 + t;
            v[t] = x[(size_t)(b * S + s) * H + h] + (1.0f - mask[b * S + s]) * (-1000.0f);
        }
#pragma unroll
        for (int t = 0; t < 8; ++t) {
            float s = v[t], q = v[t] * v[t];
            for (int o = 1; o < 64; o <<= 1) { s += __shfl_xor(s, o); q += __shfl_xor(q, o); }
            if (lane == 0) { part[wave][t][0] = s; part[wave][t][1] = q; }
        }
        __syncthreads();
        if (h < 16) {
            int row = h >> 1, st = h & 1;
            float a = 0.0f;
#pragma unroll
            for (int w = 0; w < 8; ++w) a += part[w][row][st];
            rstat[row][st] = a;
        }
        __syncthreads();
#pragma unroll
        for (int t = 0; t < 8; ++t) {
            float m = rstat[t][0] * (1.0f / 512.0f);
            float var = rstat[t][1] * (1.0f / 512.0f) - m * m;
            var = var < 0.0f ? 0.0f : var;
            float inv = rsqrtf(var + EPSF);
            ln1[(size_t)(b * S + s0 + t) * H + h] = (v[t] - m) * inv;
        }
    } else {
        int n = blockIdx.x - 64;
        if (n < 1024) {
            int k = threadIdx.x;
            int tt = n >> 7, c = n & 127;
            int h = tt * 64 + (c & 63);
            float v = (c < 64) ? Wg2[(size_t)k * H + h] : Wb2[(size_t)k * H + h];
            wcatT[(size_t)n * H + k] = __float2bfloat16(v);
        } else {
            int p = (n - 1024) * 512 + threadIdx.x;
            if (p >= P) return;
            float disc = 513.0f * 513.0f - 8.0f * (float)p;
            int i = (int)((513.0f - sqrtf(disc)) * 0.5f);
            i = i < 0 ? 0 : (i > S - 1 ? S - 1 : i);
            while (i > 0 && (i * S - i * (i - 1) / 2) > p) --i;
            while (i < S - 1 && ((i + 1) * S - (i + 1) * i / 2) <= p) ++i;
            int off = i * S - i * (i - 1) / 2;
            ii[p] = (unsigned short)i;
            jj[p] = (unsigned short)(i + (p - off));
        }
    }
}

// ---------------- G1/B1 = bias + seq @ W1 (seq inline; k-unroll x8) ----------------
__global__ __launch_bounds__(256) void g1b1_kernel(
    const float* __restrict__ x, const float* __restrict__ mask,
    const float* __restrict__ Wg1, const float* __restrict__ Wb1,
    const float* __restrict__ g1, const float* __restrict__ b1,
    float* __restrict__ G1, float* __restrict__ B1) {
    __shared__ float rowbuf[4][H];
    int grp = blockIdx.x;   // 0..127
    int mat = blockIdx.y;   // 0..1
    int tid = threadIdx.x;
    int h0 = tid, h1 = tid + 256;
    int r0 = grp * 4;
#pragma unroll
    for (int r = 0; r < 4; ++r) {
        int row = r0 + r;
        float add = (1.0f - mask[row]) * (-1000.0f);
        rowbuf[r][h0] = x[(size_t)row * H + h0] + add;
        rowbuf[r][h1] = x[(size_t)row * H + h1] + add;
    }
    __syncthreads();
    const float* W = mat ? Wb1 : Wg1;
    float acc[4][2] = {{0, 0}, {0, 0}, {0, 0}, {0, 0}};
    for (int k8 = 0; k8 < 64; ++k8) {
        float4 ra[4][2];
#pragma unroll
        for (int r = 0; r < 4; ++r) {
            ra[r][0] = ((const float4*)rowbuf[r])[k8 * 2];
            ra[r][1] = ((const float4*)rowbuf[r])[k8 * 2 + 1];
        }
        float w0[8], w1[8];
#pragma unroll
        for (int kk = 0; kk < 8; ++kk) {
            w0[kk] = W[(size_t)(k8 * 8 + kk) * H + h0];
            w1[kk] = W[(size_t)(k8 * 8 + kk) * H + h1];
        }
#pragma unroll
        for (int r = 0; r < 4; ++r) {
            acc[r][0] += ra[r][0].x * w0[0] + ra[r][0].y * w0[1] +
                         ra[r][0].z * w0[2] + ra[r][0].w * w0[3] +
                         ra[r][1].x * w0[4] + ra[r][1].y * w0[5] +
                         ra[r][1].z * w0[6] + ra[r][1].w * w0[7];
            acc[r][1] += ra[r][0].x * w1[0] + ra[r][0].y * w1[1] +
                         ra[r][0].z * w1[2] + ra[r][0].w * w1[3] +
                         ra[r][1].x * w1[4] + ra[r][1].y * w1[5] +
                         ra[r][1].z * w1[6] + ra[r][1].w * w1[7];
        }
    }
    float bias0 = (mat ? b1 : g1)[h0];
    float bias1 = (mat ? b1 : g1)[h1];
    float* dst = mat ? B1 : G1;
#pragma unroll
    for (int r = 0; r < 4; ++r) {
        dst[(size_t)(r0 + r) * H + h0] = acc[r][0] + bias0;
        dst[(size_t)(r0 + r) * H + h1] = acc[r][1] + bias1;
    }
}

// ---------------- co-scheduled: inner (even ids) | LN2 row stats (odd ids) ----------------
__global__ __launch_bounds__(256) void innerstats_kernel(
    const float* __restrict__ x, const float* __restrict__ mask,
    const float* __restrict__ lamtha,
    const float* __restrict__ ln1, const float* __restrict__ G1,
    const float* __restrict__ B1,
    bf16* __restrict__ inner, float* __restrict__ mu2, float* __restrict__ inv2) {
    __shared__ float sh_a[256];
    __shared__ float sh_b[256];
    int id = blockIdx.x;
    int kind = id & 1, sub = id >> 1;
    int t = sub & 255, b = sub >> 8;
    int i = b ? (255 - t) : t;
    int tid = threadIdx.x;
    int off = i * S - i * (i - 1) / 2;

    if (kind == 0) {
        // ---- inner ----
        int h2 = tid;                 // float2 index, 0..255
        sh_a[tid] = (1.0f - mask[b * S + tid]) * (-1000.0f);
        sh_b[tid] = 1.0f / (float)(tid + 1);
        __syncthreads();
        float2 lam = ((const float2*)lamtha)[h2];
        float2 oml = {1.0f - lam.x, 1.0f - lam.y};
        const float2* xb = (const float2*)(x + (size_t)b * S * H);
        float2 mrun = {NEGF, NEGF};
        float2 srun = {0.0f, 0.0f};
        size_t base = (size_t)b * P + (size_t)off;
        __hip_bfloat162* dst = (__hip_bfloat162*)inner;
        int j = i;
#define INNER_STEP(xx, jx)                                                 \
    {                                                                      \
        float ma = sh_a[jx];                                               \
        float vx = xx.x + ma, vy = xx.y + ma;                              \
        srun.x += vx;                                                      \
        srun.y += vy;                                                      \
        mrun.x = fmaxf(mrun.x, vx);                                        \
        mrun.y = fmaxf(mrun.y, vy);                                        \
        float rl = sh_b[(jx) - i];                                         \
        float fx = lam.x * (srun.x * rl) + oml.x * mrun.x;                 \
        float fy = lam.y * (srun.y * rl) + oml.y * mrun.y;                 \
        dst[(base + (size_t)((jx) - i)) * 256 + h2] =                      \
            __float22bfloat162_rn(make_float2(fx, fy));                    \
    }
        for (; j + 4 <= S; j += 4) {
            float2 x0 = xb[(j + 0) * 256 + h2];
            float2 x1 = xb[(j + 1) * 256 + h2];
            float2 x2 = xb[(j + 2) * 256 + h2];
            float2 x3 = xb[(j + 3) * 256 + h2];
            INNER_STEP(x0, j + 0)
            INNER_STEP(x1, j + 1)
            INNER_STEP(x2, j + 2)
            INNER_STEP(x3, j + 3)
        }
        for (; j < S; ++j) {
            float2 xv = xb[j * 256 + h2];
            INNER_STEP(xv, j)
        }
#undef INNER_STEP
    } else {
        // ---- stats (i-centric, register-pinned G1/B1) ----
        int wave = tid >> 6, lane = tid & 63;
        const float4* gp = (const float4*)(G1 + (size_t)(b * S + i) * H);
        const float4* bp = (const float4*)(B1 + (size_t)(b * S + i) * H);
        float4 ga = gp[lane * 2], gb = gp[lane * 2 + 1];
        float4 ba = bp[lane * 2], bb = bp[lane * 2 + 1];
        for (int j = i + wave; j < S; j += 4) {
            const float4* lp = (const float4*)(ln1 + (size_t)(b * S + j) * H);
            float4 a0 = lp[lane * 2], a1 = lp[lane * 2 + 1];
            float v0 = a0.x * ga.x + ba.x, v1 = a0.y * ga.y + ba.y;
            float v2 = a0.z * ga.z + ba.z, v3 = a0.w * ga.w + ba.w;
            float v4 = a1.x * gb.x + bb.x, v5 = a1.y * gb.y + bb.y;
            float v6 = a1.z * gb.z + bb.z, v7 = a1.w * gb.w + bb.w;
            float sum = ((v0 + v1) + (v2 + v3)) + ((v4 + v5) + (v6 + v7));
            float ss = ((v0 * v0 + v1 * v1) + (v2 * v2 + v3 * v3)) +
                       ((v4 * v4 + v5 * v5) + (v6 * v6 + v7 * v7));
            for (int o = 1; o < 64; o <<= 1) { sum += __shfl_xor(sum, o); ss += __shfl_xor(ss, o); }
            if (lane == 0) {
                int r = b * P + off + (j - i);
                float m = sum * (1.0f / 512.0f);
                float var = ss * (1.0f / 512.0f) - m * m;
                var = var < 0.0f ? 0.0f : var;
                mu2[r] = m;
                inv2[r] = rsqrtf(var + EPSF);
            }
        }
    }
}

// ---------------- fused GEMM (inner @ [Wg2|Wb2]) + LN2 epilogue ----------------
// 128x128 tile, 4 waves (2M x 2N) — R3's proven shape — but BK=32 with the
// R5/R10 hardware-verified paired-row XOR layout: LDS = 2 dbuf x (8K A + 8K B)
// = 32 KB -> 3 blocks/CU at __launch_bounds__(256,3) (12 waves/CU, vs R3's 8).
// Theory: true MfmaUtil is ~8.5% (derived) — kernel is LATENCY-bound; the 3rd
// co-resident block hides vmcnt waits + epilogue scatter that 2 blocks can't.
// Paired rows: phys row pr (128 B) holds logical rows 2pr,2pr+1; 16B chunk at
// phys pos pc = l ^ (pr&7), l = ((row&1)<<2)|colquad. All fragment phys bases
// are ==0 mod 8 rows -> read-side swizzle term lane-constant (R5-verified).
// Pipeline: R3 shape at 16 K-steps; stage kt+2 mid-step; steady vmcnt(4).
// Grid 4112 = 514 panels x 8 htiles, R3 decode (panel's htiles on one XCD).
__global__ __launch_bounds__(256, 3) void gemm_kernel(
    const bf16* __restrict__ inner, const bf16* __restrict__ wcatT,
    const float* __restrict__ g2, const float* __restrict__ b2,
    const float* __restrict__ ln1, const float* __restrict__ G1, const float* __restrict__ B1,
    const unsigned short* __restrict__ ii, const unsigned short* __restrict__ jj,
    const float* __restrict__ mu2, const float* __restrict__ inv2,
    float* __restrict__ out) {
    extern __shared__ __align__(16) char smem[];   // 32768: 2 bufs x (A 8K | B 8K)

    const int tid = threadIdx.x;
    const int wave = tid >> 6, lane = tid & 63;
    const int q = lane >> 4, l15 = lane & 15;
    const int wm = wave & 1, wn = wave >> 1;       // wm 0..1, wn 0..1

    const int id = blockIdx.x;
    int rb, t;
    if (id < 4096) { rb = (id >> 6) * 8 + (id & 7); t = (id >> 3) & 7; }
    else           { int w = id - 4096; rb = 512 + (w & 1); t = w >> 1; }
    const int R0 = rb * 128;

    // staging source decode (inverse of paired-row swizzle): chunk ci ->
    // pr = ci>>3, pc = ci&7, l = pc ^ (pr&7); row = 2pr + (l>>2), cq = l&3.
    int arow[2], acq[2];
#pragma unroll
    for (int s2 = 0; s2 < 2; ++s2) {
        int ci = s2 * 256 + tid;
        int pr = ci >> 3, pc = ci & 7, l = pc ^ (pr & 7);
        arow[s2] = (pr << 1) | (l >> 2);
        acq[s2] = l & 3;
    }
    const bf16* const Asrc0 = inner + (size_t)(R0 + arow[0]) * H + acq[0] * 8;
    const bf16* const Asrc1 = inner + (size_t)(R0 + arow[1]) * H + acq[1] * 8;
    const bf16* const Bsrc0 = wcatT + (size_t)(t * 128 + arow[0]) * H + acq[0] * 8;
    const bf16* const Bsrc1 = wcatT + (size_t)(t * 128 + arow[1]) * H + acq[1] * 8;

    char* const A0 = smem;
    char* const B0 = smem + 8192;
    char* const A1 = smem + 16384;
    char* const B1s = smem + 24576;

    // read-side lane constants (R5-verified algebra)
    const int prl = l15 >> 1;
    const int apc = ((((l15 & 1) << 2) | q) ^ prl) << 4;
    const int C = prl * 128 + apc;

    floatx4 acc[4][4];
#pragma unroll
    for (int a = 0; a < 4; ++a)
#pragma unroll
        for (int c = 0; c < 4; ++c) acc[a][c] = (floatx4){0.f, 0.f, 0.f, 0.f};

    auto STAGE = [&](int kt, char* Ad, char* Bd) {
        gld_lds16(Asrc0 + kt * 32, Ad + wave * 1024);
        gld_lds16(Asrc1 + kt * 32, Ad + 4096 + wave * 1024);
        gld_lds16(Bsrc0 + kt * 32, Bd + wave * 1024);
        gld_lds16(Bsrc1 + kt * 32, Bd + 4096 + wave * 1024);
    };

    // prologue: fill both buffers; wait only the first (4 loads stay in flight)
    STAGE(0, A0, B0);
    STAGE(1, A1, B1s);
    asm volatile("s_waitcnt vmcnt(4)" ::: "memory");
    asm volatile("s_barrier" ::: "memory");

#pragma unroll
    for (int kt = 0; kt < 16; ++kt) {
        char* const As = (kt & 1) ? A1 : A0;
        char* const Bs = (kt & 1) ? B1s : B0;

        short8 af[4], bfr[4];
#pragma unroll
        for (int fn = 0; fn < 4; ++fn) {
            int boff = (fn < 2) ? (wn * 2048 + fn * 1024)
                                : (4096 + wn * 2048 + (fn - 2) * 1024);
            bfr[fn] = *(const short8*)(Bs + boff + C);
        }
#pragma unroll
        for (int fm = 0; fm < 4; ++fm)
            af[fm] = *(const short8*)(As + wm * 4096 + fm * 1024 + C);

        __builtin_amdgcn_s_setprio(1);
#pragma unroll
        for (int fm = 0; fm < 2; ++fm)
#pragma unroll
            for (int fn = 0; fn < 4; ++fn)
                acc[fm][fn] = __builtin_amdgcn_mfma_f32_16x16x32_bf16(af[fm], bfr[fn], acc[fm][fn], 0, 0, 0);
        __builtin_amdgcn_s_setprio(0);

        if (kt < 14) {
            // all my LDS reads done -> barrier -> buffer dead, refill with kt+2
            asm volatile("s_waitcnt lgkmcnt(0)" ::: "memory");
            asm volatile("s_barrier" ::: "memory");
            STAGE(kt + 2, As, Bs);
        }

        __builtin_amdgcn_s_setprio(1);
#pragma unroll
        for (int fm = 2; fm < 4; ++fm)
#pragma unroll
            for (int fn = 0; fn < 4; ++fn)
                acc[fm][fn] = __builtin_amdgcn_mfma_f32_16x16x32_bf16(af[fm], bfr[fn], acc[fm][fn], 0, 0, 0);
        __builtin_amdgcn_s_setprio(0);

        if (kt < 14) {
            // wait kt+1's 4 loads (kt+2's 4 remain in flight across the barrier)
            asm volatile("s_waitcnt vmcnt(4)" ::: "memory");
            asm volatile("s_barrier" ::: "memory");
        } else if (kt == 14) {
            asm volatile("s_waitcnt vmcnt(0)" ::: "memory");
            asm volatile("s_barrier" ::: "memory");
        }
    }

    // ---- register-only LN2 epilogue (all 4 waves, no LDS, no barriers) ----
    float g2v[2], b2v[2];
#pragma unroll
    for (int fg = 0; fg < 2; ++fg) {
        int h = t * 64 + wn * 32 + fg * 16 + l15;
        g2v[fg] = g2[h];
        b2v[fg] = b2[h];
    }
#pragma unroll
    for (int fm = 0; fm < 4; ++fm) {
#pragma unroll
        for (int r = 0; r < 4; ++r) {
            int m = wm * 64 + fm * 16 + q * 4 + r;
            int rg = R0 + m;
            int b = (rg >= P) ? 1 : 0;
            int p = rg - b * P;
            int i = ii[p], j = jj[p];
            float mu = mu2[rg], iv = inv2[rg];
            const float* lp = ln1 + (size_t)(b * S + j) * H + t * 64 + wn * 32;
            const float* gp = G1 + (size_t)(b * S + i) * H + t * 64 + wn * 32;
            const float* bp = B1 + (size_t)(b * S + i) * H + t * 64 + wn * 32;
            float* op = out + (size_t)rg * H + t * 64 + wn * 32;
#pragma unroll
            for (int fg = 0; fg < 2; ++fg) {
                int c = fg * 16 + l15;
                float s = (lp[c] * gp[c] + bp[c] - mu) * iv;
                float G2v = acc[fm][fg][r] + g2v[fg];
                float B2v = acc[fm][fg + 2][r] + b2v[fg];
                op[c] = s * G2v + B2v;
            }
        }
    }
}

// ---------------- launcher ----------------
extern "C" void kernel_launch(void* const* d_in, const int* in_sizes, int n_in,
                              void* d_out, int out_size, void* d_ws, size_t ws_size,
                              hipStream_t stream) {
    const float* x = (const float*)d_in[0];
    const float* mask = (const float*)d_in[1];
    const float* lamtha = (const float*)d_in[2];
    const float* Wg1 = (const float*)d_in[3];
    const float* Wb1 = (const float*)d_in[4];
    const float* g1 = (const float*)d_in[5];
    const float* b1 = (const float*)d_in[6];
    const float* Wg2 = (const float*)d_in[7];
    const float* Wb2 = (const float*)d_in[8];
    const float* g2 = (const float*)d_in[9];
    const float* b2 = (const float*)d_in[10];
    float* out = (float*)d_out;

    char* ws = (char*)d_ws;
    float* ln1 = (float*)(ws + OFF_LN1);
    float* G1 = (float*)(ws + OFF_G1);
    float* B1 = (float*)(ws + OFF_B1);
    bf16* wcatT = (bf16*)(ws + OFF_WCAT);
    unsigned short* iiA = (unsigned short*)(ws + OFF_II);
    unsigned short* jjA = (unsigned short*)(ws + OFF_JJ);
    float* mu2 = (float*)(ws + OFF_MU2);
    float* inv2 = (float*)(ws + OFF_INV2);
    bf16* inner = (bf16*)(ws + OFF_INNER);

    static bool attr_set = false;
    if (!attr_set) {
        hipFuncSetAttribute((const void*)gemm_kernel,
                            hipFuncAttributeMaxDynamicSharedMemorySize, 32768);
        attr_set = true;
    }

    hipLaunchKernelGGL(fusedA_kernel, dim3(1153), dim3(512), 0, stream,
                       x, mask, ln1, Wg2, Wb2, wcatT, iiA, jjA);
    hipLaunchKernelGGL(g1b1_kernel, dim3(128, 2), dim3(256), 0, stream,
                       x, mask, Wg1, Wb1, g1, b1, G1, B1);
    hipLaunchKernelGGL(innerstats_kernel, dim3(1024), dim3(256), 0, stream,
                       x, mask, lamtha, ln1, G1, B1, inner, mu2, inv2);
    hipLaunchKernelGGL(gemm_kernel, dim3(4112), dim3(256), 32768, stream,
                       inner, wcatT, g2, b2, ln1, G1, B1, iiA, jjA, mu2, inv2, out);
}

// Round 12
// 295.246 us; speedup vs baseline: 1.0418x; 1.0360x over previous
//
#include <hip/hip_runtime.h>
#include <hip/hip_bf16.h>

typedef __hip_bfloat16 bf16;
typedef short short8 __attribute__((ext_vector_type(8)));
typedef float floatx4 __attribute__((ext_vector_type(4)));

#define S 256
#define H 512
#define P 32896            // S*(S+1)/2
#define NROWS 65792        // B*P
#define NEGF -1e30f
#define EPSF 1e-12f

// ---------------- ws layout (bytes) ----------------
#define OFF_LN1    2129920u    // f32 [B*S*H]
#define OFF_G1     3178496u    // f32 [B*S*H]
#define OFF_B1     4227072u    // f32 [B*S*H]
#define OFF_WCAT   5275648u    // bf16 [1024*512]
#define OFF_II     6324224u    // u16 [P]
#define OFF_JJ     6390016u    // u16 [P]
#define OFF_MU2    6455808u    // f32 [NROWS]
#define OFF_INV2   6718976u    // f32 [NROWS]
#define OFF_INNER  6982144u    // bf16 [NROWS*H]

// async 16B global->LDS (lane-linear dest: base + lane*16)
__device__ __forceinline__ void gld_lds16(const void* g, void* l) {
    __builtin_amdgcn_global_load_lds(
        (const __attribute__((address_space(1))) void*)g,
        (__attribute__((address_space(3))) void*)l, 16, 0, 0);
}

// ---------------- fused A: LN1 (blocks 0..63) | prep (64..1152) ----------------
// prep [R7-verified 64-col interleave]: GEMM htile t uses wcatT rows
// [t*128, t*128+128): local rows 0..63 = G2 cols t*64..t*64+63, local rows
// 64..127 = MATCHING B2 cols -> register-only LN2 epilogue in gemm.
__global__ __launch_bounds__(512) void fusedA_kernel(
    const float* __restrict__ x, const float* __restrict__ mask,
    float* __restrict__ ln1,
    const float* __restrict__ Wg2, const float* __restrict__ Wb2,
    bf16* __restrict__ wcatT,
    unsigned short* __restrict__ ii, unsigned short* __restrict__ jj) {
    __shared__ float part[8][8][2];
    __shared__ float rstat[8][2];
    if (blockIdx.x < 64) {
        // ---- LN1 (8 s-rows per block); seq computed inline ----
        int b = blockIdx.x >> 5, sc = blockIdx.x & 31, h = threadIdx.x;
        int wave = h >> 6, lane = h & 63;
        int s0 = sc * 8;
        float v[8];
#pragma unroll
        for (int t = 0; t < 8; ++t) {
            int s = s0 + t;
            v[t] = x[(size_t)(b * S + s) * H + h] + (1.0f - mask[b * S + s]) * (-1000.0f);
        }
#pragma unroll
        for (int t = 0; t < 8; ++t) {
            float s = v[t], q = v[t] * v[t];
            for (int o = 1; o < 64; o <<= 1) { s += __shfl_xor(s, o); q += __shfl_xor(q, o); }
            if (lane == 0) { part[wave][t][0] = s; part[wave][t][1] = q; }
        }
        __syncthreads();
        if (h < 16) {
            int row = h >> 1, st = h & 1;
            float a = 0.0f;
#pragma unroll
            for (int w = 0; w < 8; ++w) a += part[w][row][st];
            rstat[row][st] = a;
        }
        __syncthreads();
#pragma unroll
        for (int t = 0; t < 8; ++t) {
            float m = rstat[t][0] * (1.0f / 512.0f);
            float var = rstat[t][1] * (1.0f / 512.0f) - m * m;
            var = var < 0.0f ? 0.0f : var;
            float inv = rsqrtf(var + EPSF);
            ln1[(size_t)(b * S + s0 + t) * H + h] = (v[t] - m) * inv;
        }
    } else {
        int n = blockIdx.x - 64;
        if (n < 1024) {
            int k = threadIdx.x;
            int tt = n >> 7, c = n & 127;
            int h = tt * 64 + (c & 63);
            float v = (c < 64) ? Wg2[(size_t)k * H + h] : Wb2[(size_t)k * H + h];
            wcatT[(size_t)n * H + k] = __float2bfloat16(v);
        } else {
            int p = (n - 1024) * 512 + threadIdx.x;
            if (p >= P) return;
            float disc = 513.0f * 513.0f - 8.0f * (float)p;
            int i = (int)((513.0f - sqrtf(disc)) * 0.5f);
            i = i < 0 ? 0 : (i > S - 1 ? S - 1 : i);
            while (i > 0 && (i * S - i * (i - 1) / 2) > p) --i;
            while (i < S - 1 && ((i + 1) * S - (i + 1) * i / 2) <= p) ++i;
            int off = i * S - i * (i - 1) / 2;
            ii[p] = (unsigned short)i;
            jj[p] = (unsigned short)(i + (p - off));
        }
    }
}

// ---------------- G1/B1 = bias + seq @ W1 (seq inline; k-unroll x8) ----------------
__global__ __launch_bounds__(256) void g1b1_kernel(
    const float* __restrict__ x, const float* __restrict__ mask,
    const float* __restrict__ Wg1, const float* __restrict__ Wb1,
    const float* __restrict__ g1, const float* __restrict__ b1,
    float* __restrict__ G1, float* __restrict__ B1) {
    __shared__ float rowbuf[4][H];
    int grp = blockIdx.x;   // 0..127
    int mat = blockIdx.y;   // 0..1
    int tid = threadIdx.x;
    int h0 = tid, h1 = tid + 256;
    int r0 = grp * 4;
#pragma unroll
    for (int r = 0; r < 4; ++r) {
        int row = r0 + r;
        float add = (1.0f - mask[row]) * (-1000.0f);
        rowbuf[r][h0] = x[(size_t)row * H + h0] + add;
        rowbuf[r][h1] = x[(size_t)row * H + h1] + add;
    }
    __syncthreads();
    const float* W = mat ? Wb1 : Wg1;
    float acc[4][2] = {{0, 0}, {0, 0}, {0, 0}, {0, 0}};
    for (int k8 = 0; k8 < 64; ++k8) {
        float4 ra[4][2];
#pragma unroll
        for (int r = 0; r < 4; ++r) {
            ra[r][0] = ((const float4*)rowbuf[r])[k8 * 2];
            ra[r][1] = ((const float4*)rowbuf[r])[k8 * 2 + 1];
        }
        float w0[8], w1[8];
#pragma unroll
        for (int kk = 0; kk < 8; ++kk) {
            w0[kk] = W[(size_t)(k8 * 8 + kk) * H + h0];
            w1[kk] = W[(size_t)(k8 * 8 + kk) * H + h1];
        }
#pragma unroll
        for (int r = 0; r < 4; ++r) {
            acc[r][0] += ra[r][0].x * w0[0] + ra[r][0].y * w0[1] +
                         ra[r][0].z * w0[2] + ra[r][0].w * w0[3] +
                         ra[r][1].x * w0[4] + ra[r][1].y * w0[5] +
                         ra[r][1].z * w0[6] + ra[r][1].w * w0[7];
            acc[r][1] += ra[r][0].x * w1[0] + ra[r][0].y * w1[1] +
                         ra[r][0].z * w1[2] + ra[r][0].w * w1[3] +
                         ra[r][1].x * w1[4] + ra[r][1].y * w1[5] +
                         ra[r][1].z * w1[6] + ra[r][1].w * w1[7];
        }
    }
    float bias0 = (mat ? b1 : g1)[h0];
    float bias1 = (mat ? b1 : g1)[h1];
    float* dst = mat ? B1 : G1;
#pragma unroll
    for (int r = 0; r < 4; ++r) {
        dst[(size_t)(r0 + r) * H + h0] = acc[r][0] + bias0;
        dst[(size_t)(r0 + r) * H + h1] = acc[r][1] + bias1;
    }
}

// ---------------- co-scheduled: inner (even ids) | LN2 row stats (odd ids) ----------------
// inner j-loop unroll x8 (16 loads in flight; FP order per element unchanged).
__global__ __launch_bounds__(256) void innerstats_kernel(
    const float* __restrict__ x, const float* __restrict__ mask,
    const float* __restrict__ lamtha,
    const float* __restrict__ ln1, const float* __restrict__ G1,
    const float* __restrict__ B1,
    bf16* __restrict__ inner, float* __restrict__ mu2, float* __restrict__ inv2) {
    __shared__ float sh_a[256];
    __shared__ float sh_b[256];
    int id = blockIdx.x;
    int kind = id & 1, sub = id >> 1;
    int t = sub & 255, b = sub >> 8;
    int i = b ? (255 - t) : t;
    int tid = threadIdx.x;
    int off = i * S - i * (i - 1) / 2;

    if (kind == 0) {
        // ---- inner ----
        int h2 = tid;                 // float2 index, 0..255
        sh_a[tid] = (1.0f - mask[b * S + tid]) * (-1000.0f);
        sh_b[tid] = 1.0f / (float)(tid + 1);
        __syncthreads();
        float2 lam = ((const float2*)lamtha)[h2];
        float2 oml = {1.0f - lam.x, 1.0f - lam.y};
        const float2* xb = (const float2*)(x + (size_t)b * S * H);
        float2 mrun = {NEGF, NEGF};
        float2 srun = {0.0f, 0.0f};
        size_t base = (size_t)b * P + (size_t)off;
        __hip_bfloat162* dst = (__hip_bfloat162*)inner;
        int j = i;
#define INNER_STEP(xx, jx)                                                 \
    {                                                                      \
        float ma = sh_a[jx];                                               \
        float vx = xx.x + ma, vy = xx.y + ma;                              \
        srun.x += vx;                                                      \
        srun.y += vy;                                                      \
        mrun.x = fmaxf(mrun.x, vx);                                        \
        mrun.y = fmaxf(mrun.y, vy);                                        \
        float rl = sh_b[(jx) - i];                                         \
        float fx = lam.x * (srun.x * rl) + oml.x * mrun.x;                 \
        float fy = lam.y * (srun.y * rl) + oml.y * mrun.y;                 \
        dst[(base + (size_t)((jx) - i)) * 256 + h2] =                      \
            __float22bfloat162_rn(make_float2(fx, fy));                    \
    }
        for (; j + 8 <= S; j += 8) {
            float2 x0 = xb[(j + 0) * 256 + h2];
            float2 x1 = xb[(j + 1) * 256 + h2];
            float2 x2 = xb[(j + 2) * 256 + h2];
            float2 x3 = xb[(j + 3) * 256 + h2];
            float2 x4 = xb[(j + 4) * 256 + h2];
            float2 x5 = xb[(j + 5) * 256 + h2];
            float2 x6 = xb[(j + 6) * 256 + h2];
            float2 x7 = xb[(j + 7) * 256 + h2];
            INNER_STEP(x0, j + 0)
            INNER_STEP(x1, j + 1)
            INNER_STEP(x2, j + 2)
            INNER_STEP(x3, j + 3)
            INNER_STEP(x4, j + 4)
            INNER_STEP(x5, j + 5)
            INNER_STEP(x6, j + 6)
            INNER_STEP(x7, j + 7)
        }
        for (; j + 4 <= S; j += 4) {
            float2 x0 = xb[(j + 0) * 256 + h2];
            float2 x1 = xb[(j + 1) * 256 + h2];
            float2 x2 = xb[(j + 2) * 256 + h2];
            float2 x3 = xb[(j + 3) * 256 + h2];
            INNER_STEP(x0, j + 0)
            INNER_STEP(x1, j + 1)
            INNER_STEP(x2, j + 2)
            INNER_STEP(x3, j + 3)
        }
        for (; j < S; ++j) {
            float2 xv = xb[j * 256 + h2];
            INNER_STEP(xv, j)
        }
#undef INNER_STEP
    } else {
        // ---- stats (i-centric, register-pinned G1/B1) ----
        int wave = tid >> 6, lane = tid & 63;
        const float4* gp = (const float4*)(G1 + (size_t)(b * S + i) * H);
        const float4* bp = (const float4*)(B1 + (size_t)(b * S + i) * H);
        float4 ga = gp[lane * 2], gb = gp[lane * 2 + 1];
        float4 ba = bp[lane * 2], bb = bp[lane * 2 + 1];
        for (int j = i + wave; j < S; j += 4) {
            const float4* lp = (const float4*)(ln1 + (size_t)(b * S + j) * H);
            float4 a0 = lp[lane * 2], a1 = lp[lane * 2 + 1];
            float v0 = a0.x * ga.x + ba.x, v1 = a0.y * ga.y + ba.y;
            float v2 = a0.z * ga.z + ba.z, v3 = a0.w * ga.w + ba.w;
            float v4 = a1.x * gb.x + bb.x, v5 = a1.y * gb.y + bb.y;
            float v6 = a1.z * gb.z + bb.z, v7 = a1.w * gb.w + bb.w;
            float sum = ((v0 + v1) + (v2 + v3)) + ((v4 + v5) + (v6 + v7));
            float ss = ((v0 * v0 + v1 * v1) + (v2 * v2 + v3 * v3)) +
                       ((v4 * v4 + v5 * v5) + (v6 * v6 + v7 * v7));
            for (int o = 1; o < 64; o <<= 1) { sum += __shfl_xor(sum, o); ss += __shfl_xor(ss, o); }
            if (lane == 0) {
                int r = b * P + off + (j - i);
                float m = sum * (1.0f / 512.0f);
                float var = ss * (1.0f / 512.0f) - m * m;
                var = var < 0.0f ? 0.0f : var;
                mu2[r] = m;
                inv2[r] = rsqrtf(var + EPSF);
            }
        }
    }
}

// ---------------- fused GEMM (inner @ [Wg2|Wb2]) + LN2 epilogue ----------------
// R3/R7 structure EXACTLY (measured 96-98 us) with kt=7 PEELED: after kt=6's
// vmcnt(0) drain (the only point with zero staging loads in flight), prefetch
// the epilogue scalar chain (ii/jj/mu2/inv2 for all 16 slots) so those L2
// loads retire under kt=7's ds_read+MFMA instead of heading the epilogue's
// dependency chains. Pipeline counts untouched (no VMEM between the counted
// vmcnt waits). 128x128 tile, 4 waves, BK=64, 64 KB dbuf -> 2 blocks/CU.
__global__ __launch_bounds__(256, 2) void gemm_kernel(
    const bf16* __restrict__ inner, const bf16* __restrict__ wcatT,
    const float* __restrict__ g2, const float* __restrict__ b2,
    const float* __restrict__ ln1, const float* __restrict__ G1, const float* __restrict__ B1,
    const unsigned short* __restrict__ ii, const unsigned short* __restrict__ jj,
    const float* __restrict__ mu2, const float* __restrict__ inv2,
    float* __restrict__ out) {
    extern __shared__ __align__(16) char smem[];   // 65536: 2 bufs x (A 16K | B 16K)

    const int tid = threadIdx.x;
    const int wave = tid >> 6, lane = tid & 63;
    const int q = lane >> 4, l15 = lane & 15;
    const int wm = wave & 1, wn = wave >> 1;       // wm 0..1, wn 0..1

    const int id = blockIdx.x;
    int rb, t;
    if (id < 4096) { rb = (id >> 6) * 8 + (id & 7); t = (id >> 3) & 7; }
    else           { int w = id - 4096; rb = 512 + (w & 1); t = w >> 1; }
    const int R0 = rb * 128;

    const int srow = tid >> 3;                    // 0..31
    const int sx8 = ((tid & 7) ^ (srow & 7)) * 8;
    const bf16* const Ag = inner + (size_t)(R0 + srow) * H + sx8;
    const bf16* const Bg = wcatT + (size_t)(t * 128 + srow) * H + sx8;

    char* const A0 = smem;
    char* const B0 = smem + 16384;
    char* const A1 = smem + 32768;
    char* const B1s = smem + 49152;

    floatx4 acc[4][4];
#pragma unroll
    for (int a = 0; a < 4; ++a)
#pragma unroll
        for (int c = 0; c < 4; ++c) acc[a][c] = (floatx4){0.f, 0.f, 0.f, 0.f};

    auto STAGE = [&](int kt, char* Ad, char* Bd) {
#pragma unroll
        for (int i2 = 0; i2 < 4; ++i2)
            gld_lds16(Ag + (size_t)i2 * 32 * H + kt * 64, Ad + i2 * 4096 + wave * 1024);
#pragma unroll
        for (int i2 = 0; i2 < 4; ++i2)
            gld_lds16(Bg + (size_t)i2 * 32 * H + kt * 64, Bd + i2 * 4096 + wave * 1024);
    };

    STAGE(0, A0, B0);
    STAGE(1, A1, B1s);
    asm volatile("s_waitcnt vmcnt(8)" ::: "memory");
    asm volatile("s_barrier" ::: "memory");

#pragma unroll
    for (int kt = 0; kt < 7; ++kt) {               // kt=7 peeled below
        char* const As = (kt & 1) ? A1 : A0;
        char* const Bs = (kt & 1) ? B1s : B0;

        short8 bfr[4][2], af[4][2];
#pragma unroll
        for (int ks = 0; ks < 2; ++ks) {
#pragma unroll
            for (int fn = 0; fn < 4; ++fn) {
                int nr = (fn < 2 ? wn * 32 + fn * 16 : 64 + wn * 32 + (fn - 2) * 16) + l15;
                bfr[fn][ks] = *(const short8*)(Bs + nr * 128 + (((ks * 4 + q) ^ (l15 & 7)) << 4));
            }
#pragma unroll
            for (int fm = 0; fm < 4; ++fm) {
                int mr = wm * 64 + fm * 16 + l15;
                af[fm][ks] = *(const short8*)(As + mr * 128 + (((ks * 4 + q) ^ (l15 & 7)) << 4));
            }
        }

        __builtin_amdgcn_s_setprio(1);
#pragma unroll
        for (int fm = 0; fm < 4; ++fm)
#pragma unroll
            for (int fn = 0; fn < 4; ++fn)
                acc[fm][fn] = __builtin_amdgcn_mfma_f32_16x16x32_bf16(af[fm][0], bfr[fn][0], acc[fm][fn], 0, 0, 0);
        __builtin_amdgcn_s_setprio(0);

        if (kt < 6) {
            asm volatile("s_waitcnt lgkmcnt(0)" ::: "memory");
            asm volatile("s_barrier" ::: "memory");
            STAGE(kt + 2, As, Bs);
        }

        __builtin_amdgcn_s_setprio(1);
#pragma unroll
        for (int fm = 0; fm < 4; ++fm)
#pragma unroll
            for (int fn = 0; fn < 4; ++fn)
                acc[fm][fn] = __builtin_amdgcn_mfma_f32_16x16x32_bf16(af[fm][1], bfr[fn][1], acc[fm][fn], 0, 0, 0);
        __builtin_amdgcn_s_setprio(0);

        if (kt < 6) {
            asm volatile("s_waitcnt vmcnt(8)" ::: "memory");
            asm volatile("s_barrier" ::: "memory");
        } else {                                   // kt == 6: full drain
            asm volatile("s_waitcnt vmcnt(0)" ::: "memory");
            asm volatile("s_barrier" ::: "memory");
        }
    }

    // ---- epilogue scalar prefetch (staging fully drained; safe VMEM window) ----
    int ipre[4][4], jpre[4][4];
    float mupre[4][4], ivpre[4][4];
#pragma unroll
    for (int fm = 0; fm < 4; ++fm) {
#pragma unroll
        for (int r = 0; r < 4; ++r) {
            int m = wm * 64 + fm * 16 + q * 4 + r;
            int rg = R0 + m;
            int b = (rg >= P) ? 1 : 0;
            int p = rg - b * P;
            ipre[fm][r] = ii[p];
            jpre[fm][r] = jj[p];
            mupre[fm][r] = mu2[rg];
            ivpre[fm][r] = inv2[rg];
        }
    }

    // ---- peeled kt = 7 (buffers A1/B1s; no barriers or stages needed) ----
    {
        char* const As = A1;
        char* const Bs = B1s;
        short8 bfr[4][2], af[4][2];
#pragma unroll
        for (int ks = 0; ks < 2; ++ks) {
#pragma unroll
            for (int fn = 0; fn < 4; ++fn) {
                int nr = (fn < 2 ? wn * 32 + fn * 16 : 64 + wn * 32 + (fn - 2) * 16) + l15;
                bfr[fn][ks] = *(const short8*)(Bs + nr * 128 + (((ks * 4 + q) ^ (l15 & 7)) << 4));
            }
#pragma unroll
            for (int fm = 0; fm < 4; ++fm) {
                int mr = wm * 64 + fm * 16 + l15;
                af[fm][ks] = *(const short8*)(As + mr * 128 + (((ks * 4 + q) ^ (l15 & 7)) << 4));
            }
        }
        __builtin_amdgcn_s_setprio(1);
#pragma unroll
        for (int ks = 0; ks < 2; ++ks)
#pragma unroll
            for (int fm = 0; fm < 4; ++fm)
#pragma unroll
                for (int fn = 0; fn < 4; ++fn)
                    acc[fm][fn] = __builtin_amdgcn_mfma_f32_16x16x32_bf16(af[fm][ks], bfr[fn][ks], acc[fm][fn], 0, 0, 0);
        __builtin_amdgcn_s_setprio(0);
    }

    // ---- register-only LN2 epilogue (prefetched scalars; no LDS, no barriers) ----
    float g2v[2], b2v[2];
#pragma unroll
    for (int fg = 0; fg < 2; ++fg) {
        int h = t * 64 + wn * 32 + fg * 16 + l15;
        g2v[fg] = g2[h];
        b2v[fg] = b2[h];
    }
#pragma unroll
    for (int fm = 0; fm < 4; ++fm) {
#pragma unroll
        for (int r = 0; r < 4; ++r) {
            int m = wm * 64 + fm * 16 + q * 4 + r;
            int rg = R0 + m;
            int b = (rg >= P) ? 1 : 0;
            int i = ipre[fm][r], j = jpre[fm][r];
            float mu = mupre[fm][r], iv = ivpre[fm][r];
            const float* lp = ln1 + (size_t)(b * S + j) * H + t * 64 + wn * 32;
            const float* gp = G1 + (size_t)(b * S + i) * H + t * 64 + wn * 32;
            const float* bp = B1 + (size_t)(b * S + i) * H + t * 64 + wn * 32;
            float* op = out + (size_t)rg * H + t * 64 + wn * 32;
#pragma unroll
            for (int fg = 0; fg < 2; ++fg) {
                int c = fg * 16 + l15;
                float s = (lp[c] * gp[c] + bp[c] - mu) * iv;
                float G2v = acc[fm][fg][r] + g2v[fg];
                float B2v = acc[fm][fg + 2][r] + b2v[fg];
                op[c] = s * G2v + B2v;
            }
        }
    }
}

// ---------------- launcher ----------------
extern "C" void kernel_launch(void* const* d_in, const int* in_sizes, int n_in,
                              void* d_out, int out_size, void* d_ws, size_t ws_size,
                              hipStream_t stream) {
    const float* x = (const float*)d_in[0];
    const float* mask = (const float*)d_in[1];
    const float* lamtha = (const float*)d_in[2];
    const float* Wg1 = (const float*)d_in[3];
    const float* Wb1 = (const float*)d_in[4];
    const float* g1 = (const float*)d_in[5];
    const float* b1 = (const float*)d_in[6];
    const float* Wg2 = (const float*)d_in[7];
    const float* Wb2 = (const float*)d_in[8];
    const float* g2 = (const float*)d_in[9];
    const float* b2 = (const float*)d_in[10];
    float* out = (float*)d_out;

    char* ws = (char*)d_ws;
    float* ln1 = (float*)(ws + OFF_LN1);
    float* G1 = (float*)(ws + OFF_G1);
    float* B1 = (float*)(ws + OFF_B1);
    bf16* wcatT = (bf16*)(ws + OFF_WCAT);
    unsigned short* iiA = (unsigned short*)(ws + OFF_II);
    unsigned short* jjA = (unsigned short*)(ws + OFF_JJ);
    float* mu2 = (float*)(ws + OFF_MU2);
    float* inv2 = (float*)(ws + OFF_INV2);
    bf16* inner = (bf16*)(ws + OFF_INNER);

    static bool attr_set = false;
    if (!attr_set) {
        hipFuncSetAttribute((const void*)gemm_kernel,
                            hipFuncAttributeMaxDynamicSharedMemorySize, 65536);
        attr_set = true;
    }

    hipLaunchKernelGGL(fusedA_kernel, dim3(1153), dim3(512), 0, stream,
                       x, mask, ln1, Wg2, Wb2, wcatT, iiA, jjA);
    hipLaunchKernelGGL(g1b1_kernel, dim3(128, 2), dim3(256), 0, stream,
                       x, mask, Wg1, Wb1, g1, b1, G1, B1);
    hipLaunchKernelGGL(innerstats_kernel, dim3(1024), dim3(256), 0, stream,
                       x, mask, lamtha, ln1, G1, B1, inner, mu2, inv2);
    hipLaunchKernelGGL(gemm_kernel, dim3(4112), dim3(256), 65536, stream,
                       inner, wcatT, g2, b2, ln1, G1, B1, iiA, jjA, mu2, inv2, out);
}